// Round 11
// baseline (557.511 us; speedup 1.0000x reference)
//
#include <hip/hip_runtime.h>

#define VV   50257
#define EE   512
#define HH   1024
#define TT   512
#define SS   8
#define TSS  128
#define MOOV 20

// ws layout (floats)
#define OFF_Q      0        // 1024
#define OFF_COMB   1024     // 3584 : [emb(512) | acc_enc(1024) | acc_name(1024) | acc_type(1024)]
#define OFF_DENOM  4608     // 3 : unnormalized softmax denominators (enc, name, type)
#define OFF_SUMPART 4640    // 32 slots spaced 32 floats (128 B) for k_big partial sumexp
#define OFF_CTR    6000     // 3 ints: done-counters (zeroed via hipMemsetAsync each call)
#define OFF_X      7168     // 512
#define OFF_H1     11776    // 1024
#define OFF_C1     12800    // 1024
#define OFF_GENP   13824    // 1
#define OFF_SIM    13832    // 8
#define OFF_QC     13840    // 1024
#define OFF_LOGIT  15888    // 50257 (stores exp(logit))
#define OFF_PCOPY  66148    // 50277 (scaled copy probs, zeroed each call)

#define NBIG 3142           // big-matvec blocks: 16 rows each (proven R5 shape)
#define NPF  512            // prefetch blocks appended to each front kernel

__device__ __forceinline__ float dot4(float4 a, float4 b) {
    return a.x*b.x + a.y*b.y + a.z*b.z + a.w*b.w;
}
__device__ __forceinline__ float wred(float v) {
    #pragma unroll
    for (int o = 32; o; o >>= 1) v += __shfl_down(v, o, 64);
    return v;
}
__device__ __forceinline__ float wred_all(float v) {
    #pragma unroll
    for (int o = 32; o; o >>= 1) v += __shfl_xor(v, o, 64);
    return v;
}
__device__ __forceinline__ float wmax_all(float v) {
    #pragma unroll
    for (int o = 32; o; o >>= 1) v = fmaxf(v, __shfl_xor(v, o, 64));
    return v;
}

// Prefetch slice `kidx` (of 4) of W_out into L3: grid-stride float4 reads,
// kept alive via empty inline-asm (no stores, no effect on outputs).
__device__ __forceinline__ void prefetch_wout(const float* __restrict__ W, int kidx,
                                              int pb, int tid) {
    const float4* W4 = (const float4*)W;
    const size_t total4 = (size_t)VV * HH / 4;         // 12,865,792
    size_t per = (total4 + 3) / 4;                     // 3,216,448 per kernel
    size_t start = (size_t)kidx * per;
    size_t end = start + per; if (end > total4) end = total4;
    float4 a = {0.f, 0.f, 0.f, 0.f};
    for (size_t i = start + (size_t)pb * 256 + tid; i < end; i += (size_t)NPF * 256) {
        float4 v = W4[i];
        a.x += v.x; a.y += v.y; a.z += v.z; a.w += v.w;
    }
    asm volatile("" :: "v"(a.x), "v"(a.y), "v"(a.z), "v"(a.w));
}

// R rows per wave, CH float4-chunks per lane per row; vector held in registers.
template<int R, int CH>
__device__ __forceinline__ void rowsN_dot(const float* __restrict__ W, int ld,
                                          int row0, int rowmax,
                                          const float4 vec[CH], int lane, float s[R]) {
    float4 w[R][CH];
    #pragma unroll
    for (int r = 0; r < R; ++r) {
        int row = row0 + r; if (row > rowmax) row = rowmax;
        const float4* Wr = (const float4*)(W + (size_t)row * ld);
        #pragma unroll
        for (int k = 0; k < CH; ++k) w[r][k] = Wr[lane + 64 * k];
    }
    #pragma unroll
    for (int r = 0; r < R; ++r) {
        float acc = 0.f;
        #pragma unroll
        for (int k = 0; k < CH; ++k) acc += dot4(w[r][k], vec[k]);
        s[r] = acc;
    }
}

// K1: zero scratch, copy emb, q = W_ma_attn @ emb + b  (+ prefetch slice 0)
__global__ void k_init_q(const float* __restrict__ emb, const float* __restrict__ W,
                         const float* __restrict__ bias, const float* __restrict__ Wout,
                         float* __restrict__ ws) {
    int tid = threadIdx.x, bid = blockIdx.x;
    if (bid >= 197) { prefetch_wout(Wout, 0, bid - 197, tid); return; }
    int gid = bid * 256 + tid;
    if (gid < 3072) ws[OFF_COMB + 512 + gid] = 0.f;
    if (gid < 3)    ws[OFF_DENOM + gid] = 0.f;
    if (gid < 1024) ws[OFF_SUMPART + gid] = 0.f;
    if (gid < 512)  ws[OFF_COMB + gid] = emb[gid];
    if (gid < VV + MOOV) ws[OFF_PCOPY + gid] = 0.f;
    if (bid >= 64) return;
    int wave = tid >> 6, lane = tid & 63;
    const float4* e4 = (const float4*)emb;
    float4 ev[2] = { e4[lane], e4[lane + 64] };
    int row0 = (bid * 4 + wave) * 4;                   // < 1024
    float s[4];
    rowsN_dot<4, 2>(W, EE, row0, 1023, ev, lane, s);
    #pragma unroll
    for (int r = 0; r < 4; ++r) {
        float v = wred(s[r]);
        if (lane == 0) ws[OFF_Q + row0 + r] = v + bias[row0 + r];
    }
}

// K2: fused scores + unnormalized-softmax ctx (+ sim) (+ prefetch slice 1)
__global__ void k_scores_ctx(const float* __restrict__ enc, const float* __restrict__ name,
                             const float* __restrict__ type, const float* __restrict__ Wout,
                             float* __restrict__ ws) {
    int b = blockIdx.x, tid = threadIdx.x;
    if (b >= 161) { prefetch_wout(Wout, 1, b - 161, tid); return; }
    int wave = tid >> 6, lane = tid & 63;
    if (b < 160) {
        const float* src; int seg, lb;
        if (b < 32)      { src = enc;  seg = 0; lb = b; }
        else if (b < 96) { src = name; seg = 1; lb = b - 32; }
        else             { src = type; seg = 2; lb = b - 96; }
        __shared__ float sc[16];
        const float4* q4 = (const float4*)(ws + OFF_Q);
        float4 qv[4] = { q4[lane], q4[lane + 64], q4[lane + 128], q4[lane + 192] };
        int r0 = lb * 16 + wave * 4;
        float s[4];
        rowsN_dot<4, 4>(src, HH, r0, 1 << 30, qv, lane, s);
        #pragma unroll
        for (int r = 0; r < 4; ++r) {
            float v = wred(s[r]);
            if (lane == 0) sc[wave * 4 + r] = __expf(v);
        }
        __syncthreads();
        float acc[4] = {0.f, 0.f, 0.f, 0.f};
        const float* base = src + (size_t)(lb * 16) * HH;
        #pragma unroll 4
        for (int r = 0; r < 16; ++r) {
            float er = sc[r];
            const float* row = base + (size_t)r * HH;
            #pragma unroll
            for (int c = 0; c < 4; ++c) acc[c] += er * row[tid + 256 * c];
        }
        float* dst = ws + OFF_COMB + 512 + seg * 1024;
        #pragma unroll
        for (int c = 0; c < 4; ++c) atomicAdd(&dst[tid + 256 * c], acc[c]);
        if (tid == 0) {
            float es = 0.f;
            for (int r = 0; r < 16; ++r) es += sc[r];
            atomicAdd(&ws[OFF_DENOM + seg], es);
        }
    } else {
        __shared__ float sd[8];
        const float4* el = (const float4*)(enc + (size_t)(TT - 1) * HH);
        for (int s8 = wave; s8 < 8; s8 += 4) {
            const float4* R = (const float4*)(name + ((size_t)s8 * TSS + (TSS - 1)) * HH);
            float s = 0.f;
            #pragma unroll
            for (int k = 0; k < 4; ++k) s += dot4(R[lane + 64 * k], el[lane + 64 * k]);
            s = wred(s);
            if (lane == 0) sd[s8] = s;
        }
        __syncthreads();
        if (tid == 0) {
            float m = -1e30f;
            for (int i = 0; i < 8; ++i) m = fmaxf(m, sd[i]);
            float e[8], su = 0.f;
            for (int i = 0; i < 8; ++i) { e[i] = __expf(sd[i] - m); su += e[i]; }
            for (int i = 0; i < 8; ++i) ws[OFF_SIM + i] = e[i] / su;
        }
    }
}

// K3: x = tanh(W_ma_comb @ (comb scaled by 1/denom) + b) (+ prefetch slice 2)
__global__ void k_x(const float* __restrict__ W, const float* __restrict__ bias,
                    const float* __restrict__ Wout, float* __restrict__ ws) {
    int tid = threadIdx.x, bid = blockIdx.x;
    if (bid >= 128) { prefetch_wout(Wout, 2, bid - 128, tid); return; }
    int wave = tid >> 6, lane = tid & 63;
    int row = bid * 4 + wave;                          // < 512
    float inv1 = 1.f / ws[OFF_DENOM + 0];
    float inv2 = 1.f / ws[OFF_DENOM + 1];
    float inv3 = 1.f / ws[OFF_DENOM + 2];
    const float4* Wr = (const float4*)(W + (size_t)row * 3584);
    const float4* c4 = (const float4*)(ws + OFF_COMB);
    float s = 0.f;
    #pragma unroll
    for (int k = 0; k < 14; ++k) {
        int j = lane + 64 * k;
        float sc = (j < 128) ? 1.f : (j < 384) ? inv1 : (j < 640) ? inv2 : inv3;
        s += dot4(Wr[j], c4[j]) * sc;
    }
    s = wred(s);
    if (lane == 0) ws[OFF_X + row] = tanhf(s + bias[row]);
}

// K4: fused gates + LSTM cell (+ prefetch slice 3)
__global__ void k_gates_lstm(const float* __restrict__ Wih, const float* __restrict__ Whh,
                             const float* __restrict__ bih, const float* __restrict__ bhh,
                             const float* __restrict__ h0, const float* __restrict__ c0,
                             const float* __restrict__ Wout,
                             float* __restrict__ ws, float* __restrict__ out) {
    int tid = threadIdx.x, b = blockIdx.x;
    if (b >= 64) { prefetch_wout(Wout, 3, b - 64, tid); return; }
    __shared__ float g4[4][16];
    int wave = tid >> 6, lane = tid & 63;
    const float4* x4 = (const float4*)(ws + OFF_X);
    float4 xv[2] = { x4[lane], x4[lane + 64] };
    const float4* h4 = (const float4*)h0;
    float4 hv[4] = { h4[lane], h4[lane + 64], h4[lane + 128], h4[lane + 192] };
    #pragma unroll
    for (int grp = 0; grp < 4; ++grp) {
        int row0 = wave * 1024 + b * 16 + grp * 4;
        float s1[4], s2[4];
        rowsN_dot<4, 2>(Wih, EE, row0, 4095, xv, lane, s1);
        rowsN_dot<4, 4>(Whh, HH, row0, 4095, hv, lane, s2);
        #pragma unroll
        for (int r = 0; r < 4; ++r) {
            float v = wred(s1[r] + s2[r]);
            int row = row0 + r;
            if (lane == 0) g4[wave][grp * 4 + r] = v + bih[row] + bhh[row];
        }
    }
    __syncthreads();
    if (tid < 16) {
        int t = b * 16 + tid;
        float ig = 1.f / (1.f + __expf(-g4[0][tid]));
        float fg = 1.f / (1.f + __expf(-g4[1][tid]));
        float gg = tanhf(g4[2][tid]);
        float og = 1.f / (1.f + __expf(-g4[3][tid]));
        float c1 = fg * c0[t] + ig * gg;
        float h1 = og * tanhf(c1);
        ws[OFF_H1 + t] = h1; ws[OFF_C1 + t] = c1;
        out[VV + MOOV + t] = h1;
        out[VV + MOOV + 1024 + t] = c1;
    }
}

// K5: everything h1-dependent in one kernel, ordered by dispatch + tiny spins:
// [0..63] qc  [64] genp  [65..65+NBIG) big matvec  [+8 scatter]  [+197 final]
__global__ void k_big_all(const float* __restrict__ W, const float* __restrict__ bias,
                          const float* __restrict__ Wcp, const float* __restrict__ bcp,
                          const float* __restrict__ nameh, const float* __restrict__ typeh,
                          const float* __restrict__ Wg, const float* __restrict__ bg,
                          const float* __restrict__ type, const int* __restrict__ idx,
                          float* __restrict__ ws, float* __restrict__ out) {
    int b = blockIdx.x, tid = threadIdx.x, wave = tid >> 6, lane = tid & 63;
    int* ctr = (int*)(ws + OFF_CTR);   // [0]=qc+genp done(65) [1]=big done(NBIG) [2]=scatter done(8)
    const float4* h4 = (const float4*)(ws + OFF_H1);
    if (b < 64) {
        // qc = W_copy @ h1 + b_copy
        float4 hv[4] = { h4[lane], h4[lane + 64], h4[lane + 128], h4[lane + 192] };
        int row0 = (b * 4 + wave) * 4;                 // < 1024
        float s[4];
        rowsN_dot<4, 4>(Wcp, HH, row0, 1023, hv, lane, s);
        #pragma unroll
        for (int r = 0; r < 4; ++r) {
            float v = wred(s[r]);
            if (lane == 0) ws[OFF_QC + row0 + r] = v + bcp[row0 + r];
        }
        __syncthreads();
        __threadfence();
        if (tid == 0) __hip_atomic_fetch_add(ctr, 1, __ATOMIC_ACQ_REL, __HIP_MEMORY_SCOPE_AGENT);
    } else if (b == 64) {
        // gen_p
        float p = 0.f;
        #pragma unroll
        for (int j = 0; j < 14; ++j) {
            int k = tid + 256 * j;
            float cat = (k < 1024) ? ws[OFF_H1 + k]
                      : (k < 2048) ? nameh[k - 1024]
                      : (k < 3072) ? typeh[k - 2048]
                                   : ws[OFF_X + k - 3072];
            p += Wg[k] * cat;
        }
        __shared__ float red[4];
        float su = wred_all(p);
        if ((tid & 63) == 0) red[tid >> 6] = su;
        __syncthreads();
        if (tid == 0) {
            float ss = red[0] + red[1] + red[2] + red[3];
            ws[OFF_GENP] = 1.f / (1.f + __expf(-(ss + bg[0])));
        }
        __syncthreads();
        __threadfence();
        if (tid == 0) __hip_atomic_fetch_add(ctr, 1, __ATOMIC_ACQ_REL, __HIP_MEMORY_SCOPE_AGENT);
    } else if (b < 65 + NBIG) {
        // big matvec: exp(W_out @ h1 + b_out), 16 rows per block (R5 shape)
        float4 hv[4] = { h4[lane], h4[lane + 64], h4[lane + 128], h4[lane + 192] };
        int row0 = ((b - 65) * 4 + wave) * 4;
        float s[4];
        rowsN_dot<4, 4>(W, HH, row0, VV - 1, hv, lane, s);
        float partial = 0.f;
        #pragma unroll
        for (int r = 0; r < 4; ++r) {
            float v = wred(s[r]);
            int row = row0 + r;
            if (lane == 0 && row < VV) {
                float e = __expf(v + bias[row]);
                ws[OFF_LOGIT + row] = e;
                partial += e;
            }
        }
        if (lane == 0) atomicAdd(&ws[OFF_SUMPART + (b & 31) * 32], partial);
        __syncthreads();
        __threadfence();
        if (tid == 0) __hip_atomic_fetch_add(ctr + 1, 1, __ATOMIC_ACQ_REL, __HIP_MEMORY_SCOPE_AGENT);
    } else if (b < 65 + NBIG + 8) {
        // scatter: wait for qc+genp (65 producers, dispatched first)
        if (tid == 0) {
            while (__hip_atomic_load(ctr, __ATOMIC_ACQUIRE, __HIP_MEMORY_SCOPE_AGENT) < 65)
                __builtin_amdgcn_s_sleep(8);
        }
        __syncthreads();
        __shared__ float sc[TSS];
        __shared__ float sh_m, sh_s;
        int s = b - (65 + NBIG);                       // 0..7
        const float4* q4 = (const float4*)(ws + OFF_QC);
        float4 qv[4] = { q4[lane], q4[lane + 64], q4[lane + 128], q4[lane + 192] };
        #pragma unroll
        for (int g = 0; g < 8; ++g) {
            int rloc = wave * 32 + g * 4;
            int r0 = s * TSS + rloc;
            float sv[4];
            rowsN_dot<4, 4>(type, HH, r0, 1 << 30, qv, lane, sv);
            #pragma unroll
            for (int r = 0; r < 4; ++r) {
                float v = wred(sv[r]);
                if (lane == 0) sc[rloc + r] = v;
            }
        }
        __syncthreads();
        if (wave == 0) {
            float v0 = sc[lane], v1 = sc[lane + 64];
            float m = wmax_all(fmaxf(v0, v1));
            float su = wred_all(__expf(v0 - m) + __expf(v1 - m));
            if (lane == 0) { sh_m = m; sh_s = su; }
        }
        __syncthreads();
        if (tid < TSS) {
            float scale = (1.f - ws[OFF_GENP]) * ws[OFF_SIM + s] / sh_s;
            float w = scale * __expf(sc[tid] - sh_m);
            atomicAdd(&ws[OFF_PCOPY + idx[s * TSS + tid]], w);
        }
        __syncthreads();
        __threadfence();
        if (tid == 0) __hip_atomic_fetch_add(ctr + 2, 1, __ATOMIC_ACQ_REL, __HIP_MEMORY_SCOPE_AGENT);
    } else {
        // final: wait for all big blocks + all scatter blocks
        if (tid == 0) {
            while (__hip_atomic_load(ctr + 1, __ATOMIC_ACQUIRE, __HIP_MEMORY_SCOPE_AGENT) < NBIG)
                __builtin_amdgcn_s_sleep(8);
            while (__hip_atomic_load(ctr + 2, __ATOMIC_ACQUIRE, __HIP_MEMORY_SCOPE_AGENT) < 8)
                __builtin_amdgcn_s_sleep(8);
        }
        __syncthreads();
        __shared__ float ssum;
        if (tid < 64) {
            float v = (tid < 32) ? ws[OFF_SUMPART + tid * 32] : 0.f;
            v = wred_all(v);
            if (tid == 0) ssum = v;
        }
        __syncthreads();
        int g = (b - (65 + NBIG + 8)) * 256 + tid;
        if (g < VV + MOOV) {
            float gp = ws[OFF_GENP];
            float pv = (g < VV) ? ws[OFF_LOGIT + g] / ssum : 0.f;
            float prob = gp * pv + ws[OFF_PCOPY + g];
            out[g] = logf(fmaxf(prob, 1e-10f));
        }
    }
}

extern "C" void kernel_launch(void* const* d_in, const int* in_sizes, int n_in,
                              void* d_out, int out_size, void* d_ws, size_t ws_size,
                              hipStream_t stream) {
    (void)in_sizes; (void)n_in; (void)out_size; (void)ws_size;
    const float* emb   = (const float*)d_in[0];
    const float* h0    = (const float*)d_in[1];
    const float* c0    = (const float*)d_in[2];
    const float* enc   = (const float*)d_in[3];
    const float* name  = (const float*)d_in[4];
    const float* type  = (const float*)d_in[5];
    const float* nameh = (const float*)d_in[6];
    const float* typeh = (const float*)d_in[7];
    const float* Wma   = (const float*)d_in[8];
    const float* bma   = (const float*)d_in[9];
    const float* Wmc   = (const float*)d_in[10];
    const float* bmc   = (const float*)d_in[11];
    const float* Wih   = (const float*)d_in[12];
    const float* Whh   = (const float*)d_in[13];
    const float* bih   = (const float*)d_in[14];
    const float* bhh   = (const float*)d_in[15];
    const float* Wcp   = (const float*)d_in[16];
    const float* bcp   = (const float*)d_in[17];
    const float* Wg    = (const float*)d_in[18];
    const float* bg    = (const float*)d_in[19];
    const float* Wout  = (const float*)d_in[20];
    const float* bout  = (const float*)d_in[21];
    const int*   tidx  = (const int*)d_in[22];
    float* out = (float*)d_out;
    float* ws  = (float*)d_ws;

    (void)hipMemsetAsync((char*)d_ws + OFF_CTR * sizeof(float), 0, 3 * sizeof(int), stream);

    k_init_q     <<<197 + NPF, 256, 0, stream>>>(emb, Wma, bma, Wout, ws);
    k_scores_ctx <<<161 + NPF, 256, 0, stream>>>(enc, name, type, Wout, ws);
    k_x          <<<128 + NPF, 256, 0, stream>>>(Wmc, bmc, Wout, ws);
    k_gates_lstm <<<64 + NPF,  256, 0, stream>>>(Wih, Whh, bih, bhh, h0, c0, Wout, ws, out);
    k_big_all    <<<65 + NBIG + 8 + 197, 256, 0, stream>>>(Wout, bout, Wcp, bcp, nameh, typeh,
                                                           Wg, bg, type, tidx, ws, out);
}

// Round 12
// 91.030 us; speedup vs baseline: 6.1245x; 6.1245x over previous
//
#include <hip/hip_runtime.h>

#define VV   50257
#define EE   512
#define HH   1024
#define TT   512
#define SS   8
#define TSS  128
#define MOOV 20

// ws layout (floats)
#define OFF_Q      0        // 1024
#define OFF_COMB   1024     // 3584 : [emb(512) | acc_enc(1024) | acc_name(1024) | acc_type(1024)]
#define OFF_DENOM  4608     // 3 : unnormalized softmax denominators (enc, name, type)
#define OFF_SUMPART 4640    // 32 slots spaced 32 floats (128 B) for k_big partial sumexp
#define OFF_CTR    6000     // 1 int: qc/genp done counter (zeroed via hipMemsetAsync)
#define OFF_X      7168     // 512
#define OFF_GATES  7680     // 4096 : precomputed Whh@h0 + b_ih + b_hh
#define OFF_H1     11776    // 1024
#define OFF_C1     12800    // 1024
#define OFF_GENP   13824    // 1
#define OFF_SIM    13832    // 8
#define OFF_QC     13840    // 1024
#define OFF_LOGIT  15888    // 50257 (stores exp(logit))
#define OFF_PCOPY  66148    // 50277 (scaled copy probs, zeroed each call)

#define NBIG 3142           // big-matvec blocks: 16 rows each (proven R5 shape)

__device__ __forceinline__ float dot4(float4 a, float4 b) {
    return a.x*b.x + a.y*b.y + a.z*b.z + a.w*b.w;
}
__device__ __forceinline__ float wred(float v) {
    #pragma unroll
    for (int o = 32; o; o >>= 1) v += __shfl_down(v, o, 64);
    return v;
}
__device__ __forceinline__ float wred_all(float v) {
    #pragma unroll
    for (int o = 32; o; o >>= 1) v += __shfl_xor(v, o, 64);
    return v;
}
__device__ __forceinline__ float wmax_all(float v) {
    #pragma unroll
    for (int o = 32; o; o >>= 1) v = fmaxf(v, __shfl_xor(v, o, 64));
    return v;
}

// R rows per wave, CH float4-chunks per lane per row; vector held in registers.
template<int R, int CH>
__device__ __forceinline__ void rowsN_dot(const float* __restrict__ W, int ld,
                                          int row0, int rowmax,
                                          const float4 vec[CH], int lane, float s[R]) {
    float4 w[R][CH];
    #pragma unroll
    for (int r = 0; r < R; ++r) {
        int row = row0 + r; if (row > rowmax) row = rowmax;
        const float4* Wr = (const float4*)(W + (size_t)row * ld);
        #pragma unroll
        for (int k = 0; k < CH; ++k) w[r][k] = Wr[lane + 64 * k];
    }
    #pragma unroll
    for (int r = 0; r < R; ++r) {
        float acc = 0.f;
        #pragma unroll
        for (int k = 0; k < CH; ++k) acc += dot4(w[r][k], vec[k]);
        s[r] = acc;
    }
}

// K1: ALL dependency-free work: zero scratch, copy emb, q = W_ma@emb + b,
// sim, and gates_pre = Whh@h0 + b_ih + b_hh (16 MB pulled off the critical path).
// Blocks: 0..196 zero(+q for b<64), 197 sim, 198..453 gates_pre.
__global__ void k_init(const float* __restrict__ emb, const float* __restrict__ Wma,
                       const float* __restrict__ bma, const float* __restrict__ enc,
                       const float* __restrict__ name, const float* __restrict__ Whh,
                       const float* __restrict__ bih, const float* __restrict__ bhh,
                       const float* __restrict__ h0, float* __restrict__ ws) {
    int tid = threadIdx.x, bid = blockIdx.x;
    int wave = tid >> 6, lane = tid & 63;
    if (bid < 197) {
        int gid = bid * 256 + tid;
        if (gid < 3072) ws[OFF_COMB + 512 + gid] = 0.f;
        if (gid < 3)    ws[OFF_DENOM + gid] = 0.f;
        if (gid < 1024) ws[OFF_SUMPART + gid] = 0.f;
        if (gid < 512)  ws[OFF_COMB + gid] = emb[gid];
        if (gid < VV + MOOV) ws[OFF_PCOPY + gid] = 0.f;
        if (bid >= 64) return;
        const float4* e4 = (const float4*)emb;
        float4 ev[2] = { e4[lane], e4[lane + 64] };
        int row0 = (bid * 4 + wave) * 4;               // < 1024
        float s[4];
        rowsN_dot<4, 2>(Wma, EE, row0, 1023, ev, lane, s);
        #pragma unroll
        for (int r = 0; r < 4; ++r) {
            float v = wred(s[r]);
            if (lane == 0) ws[OFF_Q + row0 + r] = v + bma[row0 + r];
        }
    } else if (bid == 197) {
        // sim = softmax(enc_last @ name_hiddens[:, -1, :].T)
        __shared__ float sd[8];
        const float4* el = (const float4*)(enc + (size_t)(TT - 1) * HH);
        for (int s8 = wave; s8 < 8; s8 += 4) {
            const float4* R = (const float4*)(name + ((size_t)s8 * TSS + (TSS - 1)) * HH);
            float s = 0.f;
            #pragma unroll
            for (int k = 0; k < 4; ++k) s += dot4(R[lane + 64 * k], el[lane + 64 * k]);
            s = wred(s);
            if (lane == 0) sd[s8] = s;
        }
        __syncthreads();
        if (tid == 0) {
            float m = -1e30f;
            for (int i = 0; i < 8; ++i) m = fmaxf(m, sd[i]);
            float e[8], su = 0.f;
            for (int i = 0; i < 8; ++i) { e[i] = __expf(sd[i] - m); su += e[i]; }
            for (int i = 0; i < 8; ++i) ws[OFF_SIM + i] = e[i] / su;
        }
    } else {
        // gates_pre: 16 rows per block, 4 rows/wave
        const float4* h4 = (const float4*)h0;
        float4 hv[4] = { h4[lane], h4[lane + 64], h4[lane + 128], h4[lane + 192] };
        int row0 = (bid - 198) * 16 + wave * 4;        // < 4096
        float s[4];
        rowsN_dot<4, 4>(Whh, HH, row0, 4095, hv, lane, s);
        #pragma unroll
        for (int r = 0; r < 4; ++r) {
            float v = wred(s[r]);
            int row = row0 + r;
            if (lane == 0) ws[OFF_GATES + row] = v + bih[row] + bhh[row];
        }
    }
}

// K2: fused scores + unnormalized-softmax context accumulation
__global__ void k_scores_ctx(const float* __restrict__ enc, const float* __restrict__ name,
                             const float* __restrict__ type, float* __restrict__ ws) {
    int b = blockIdx.x, tid = threadIdx.x;
    int wave = tid >> 6, lane = tid & 63;
    const float* src; int seg, lb;
    if (b < 32)      { src = enc;  seg = 0; lb = b; }
    else if (b < 96) { src = name; seg = 1; lb = b - 32; }
    else             { src = type; seg = 2; lb = b - 96; }
    __shared__ float sc[16];
    const float4* q4 = (const float4*)(ws + OFF_Q);
    float4 qv[4] = { q4[lane], q4[lane + 64], q4[lane + 128], q4[lane + 192] };
    int r0 = lb * 16 + wave * 4;
    float s[4];
    rowsN_dot<4, 4>(src, HH, r0, 1 << 30, qv, lane, s);
    #pragma unroll
    for (int r = 0; r < 4; ++r) {
        float v = wred(s[r]);
        if (lane == 0) sc[wave * 4 + r] = __expf(v);
    }
    __syncthreads();
    float acc[4] = {0.f, 0.f, 0.f, 0.f};
    const float* base = src + (size_t)(lb * 16) * HH;
    #pragma unroll 4
    for (int r = 0; r < 16; ++r) {
        float er = sc[r];
        const float* row = base + (size_t)r * HH;
        #pragma unroll
        for (int c = 0; c < 4; ++c) acc[c] += er * row[tid + 256 * c];
    }
    float* dst = ws + OFF_COMB + 512 + seg * 1024;
    #pragma unroll
    for (int c = 0; c < 4; ++c) atomicAdd(&dst[tid + 256 * c], acc[c]);
    if (tid == 0) {
        float es = 0.f;
        for (int r = 0; r < 16; ++r) es += sc[r];
        atomicAdd(&ws[OFF_DENOM + seg], es);
    }
}

// K3: x = tanh(W_ma_comb @ (comb with per-segment 1/denom scaling) + b)
__global__ void k_x(const float* __restrict__ W, const float* __restrict__ bias,
                    float* __restrict__ ws) {
    int tid = threadIdx.x, wave = tid >> 6, lane = tid & 63;
    int row = blockIdx.x * 4 + wave;                   // < 512
    float inv1 = 1.f / ws[OFF_DENOM + 0];
    float inv2 = 1.f / ws[OFF_DENOM + 1];
    float inv3 = 1.f / ws[OFF_DENOM + 2];
    const float4* Wr = (const float4*)(W + (size_t)row * 3584);
    const float4* c4 = (const float4*)(ws + OFF_COMB);
    float s = 0.f;
    #pragma unroll
    for (int k = 0; k < 14; ++k) {
        int j = lane + 64 * k;
        float sc = (j < 128) ? 1.f : (j < 384) ? inv1 : (j < 640) ? inv2 : inv3;
        s += dot4(Wr[j], c4[j]) * sc;
    }
    s = wred(s);
    if (lane == 0) ws[OFF_X + row] = tanhf(s + bias[row]);
}

// K4: gates (Wih@x only; Whh part precomputed in K1) + LSTM cell.
// Block b owns t in [b*16, b*16+16); wave w computes gate w's 16 rows.
__global__ void k_gates_lstm(const float* __restrict__ Wih,
                             const float* __restrict__ c0,
                             float* __restrict__ ws, float* __restrict__ out) {
    __shared__ float g4[4][16];
    int tid = threadIdx.x, wave = tid >> 6, lane = tid & 63, b = blockIdx.x;
    const float4* x4 = (const float4*)(ws + OFF_X);
    float4 xv[2] = { x4[lane], x4[lane + 64] };
    #pragma unroll
    for (int grp = 0; grp < 4; ++grp) {
        int row0 = wave * 1024 + b * 16 + grp * 4;
        float s1[4];
        rowsN_dot<4, 2>(Wih, EE, row0, 4095, xv, lane, s1);
        #pragma unroll
        for (int r = 0; r < 4; ++r) {
            float v = wred(s1[r]);
            int row = row0 + r;
            if (lane == 0) g4[wave][grp * 4 + r] = v + ws[OFF_GATES + row];
        }
    }
    __syncthreads();
    if (tid < 16) {
        int t = b * 16 + tid;
        float ig = 1.f / (1.f + __expf(-g4[0][tid]));
        float fg = 1.f / (1.f + __expf(-g4[1][tid]));
        float gg = tanhf(g4[2][tid]);
        float og = 1.f / (1.f + __expf(-g4[3][tid]));
        float c1 = fg * c0[t] + ig * gg;
        float h1 = og * tanhf(c1);
        ws[OFF_H1 + t] = h1; ws[OFF_C1 + t] = c1;
        out[VV + MOOV + t] = h1;
        out[VV + MOOV + 1024 + t] = c1;
    }
}

// K5: [0..63] qc (+fence+count)  [64] genp (+fence+count)
//     [65..65+NBIG) big matvec (NO fences)  [last 8] scatter (spin on count==65).
__global__ void k_big_all(const float* __restrict__ W, const float* __restrict__ bias,
                          const float* __restrict__ Wcp, const float* __restrict__ bcp,
                          const float* __restrict__ nameh, const float* __restrict__ typeh,
                          const float* __restrict__ Wg, const float* __restrict__ bg,
                          const float* __restrict__ type, const int* __restrict__ idx,
                          float* __restrict__ ws) {
    int b = blockIdx.x, tid = threadIdx.x, wave = tid >> 6, lane = tid & 63;
    int* ctr = (int*)(ws + OFF_CTR);
    const float4* h4 = (const float4*)(ws + OFF_H1);
    if (b < 64) {
        // qc = W_copy @ h1 + b_copy
        float4 hv[4] = { h4[lane], h4[lane + 64], h4[lane + 128], h4[lane + 192] };
        int row0 = (b * 4 + wave) * 4;                 // < 1024
        float s[4];
        rowsN_dot<4, 4>(Wcp, HH, row0, 1023, hv, lane, s);
        #pragma unroll
        for (int r = 0; r < 4; ++r) {
            float v = wred(s[r]);
            if (lane == 0) ws[OFF_QC + row0 + r] = v + bcp[row0 + r];
        }
        __syncthreads();
        __threadfence();
        if (tid == 0) __hip_atomic_fetch_add(ctr, 1, __ATOMIC_ACQ_REL, __HIP_MEMORY_SCOPE_AGENT);
    } else if (b == 64) {
        // gen_p = sigmoid(W_gen . [h1, name_h, type_h, x] + b_gen)
        float p = 0.f;
        #pragma unroll
        for (int j = 0; j < 14; ++j) {
            int k = tid + 256 * j;
            float cat = (k < 1024) ? ws[OFF_H1 + k]
                      : (k < 2048) ? nameh[k - 1024]
                      : (k < 3072) ? typeh[k - 2048]
                                   : ws[OFF_X + k - 3072];
            p += Wg[k] * cat;
        }
        __shared__ float red[4];
        float su = wred_all(p);
        if ((tid & 63) == 0) red[tid >> 6] = su;
        __syncthreads();
        if (tid == 0) {
            float ss = red[0] + red[1] + red[2] + red[3];
            ws[OFF_GENP] = 1.f / (1.f + __expf(-(ss + bg[0])));
        }
        __syncthreads();
        __threadfence();
        if (tid == 0) __hip_atomic_fetch_add(ctr, 1, __ATOMIC_ACQ_REL, __HIP_MEMORY_SCOPE_AGENT);
    } else if (b < 65 + NBIG) {
        // big matvec: exp(W_out @ h1 + b_out), 16 rows per block (R5 shape, fence-free)
        float4 hv[4] = { h4[lane], h4[lane + 64], h4[lane + 128], h4[lane + 192] };
        int row0 = ((b - 65) * 4 + wave) * 4;
        float s[4];
        rowsN_dot<4, 4>(W, HH, row0, VV - 1, hv, lane, s);
        float partial = 0.f;
        #pragma unroll
        for (int r = 0; r < 4; ++r) {
            float v = wred(s[r]);
            int row = row0 + r;
            if (lane == 0 && row < VV) {
                float e = __expf(v + bias[row]);
                ws[OFF_LOGIT + row] = e;
                partial += e;
            }
        }
        if (lane == 0) atomicAdd(&ws[OFF_SUMPART + (b & 31) * 32], partial);
    } else {
        // scatter (8 blocks): spin until qc+genp done (65 producers, dispatched first)
        if (tid == 0) {
            while (__hip_atomic_load(ctr, __ATOMIC_ACQUIRE, __HIP_MEMORY_SCOPE_AGENT) < 65)
                __builtin_amdgcn_s_sleep(8);
        }
        __syncthreads();
        __shared__ float sc[TSS];
        __shared__ float sh_m, sh_s;
        int s = b - (65 + NBIG);                       // 0..7
        const float4* q4 = (const float4*)(ws + OFF_QC);
        float4 qv[4] = { q4[lane], q4[lane + 64], q4[lane + 128], q4[lane + 192] };
        #pragma unroll
        for (int g = 0; g < 8; ++g) {
            int rloc = wave * 32 + g * 4;
            int r0 = s * TSS + rloc;
            float sv[4];
            rowsN_dot<4, 4>(type, HH, r0, 1 << 30, qv, lane, sv);
            #pragma unroll
            for (int r = 0; r < 4; ++r) {
                float v = wred(sv[r]);
                if (lane == 0) sc[rloc + r] = v;
            }
        }
        __syncthreads();
        if (wave == 0) {
            float v0 = sc[lane], v1 = sc[lane + 64];
            float m = wmax_all(fmaxf(v0, v1));
            float su = wred_all(__expf(v0 - m) + __expf(v1 - m));
            if (lane == 0) { sh_m = m; sh_s = su; }
        }
        __syncthreads();
        if (tid < TSS) {
            float scale = (1.f - ws[OFF_GENP]) * ws[OFF_SIM + s] / sh_s;
            float w = scale * __expf(sc[tid] - sh_m);
            atomicAdd(&ws[OFF_PCOPY + idx[s * TSS + tid]], w);
        }
    }
}

// K6: out[v] = log(clip(gen_p * p_vocab[v] + p_copy[v]))
__global__ void k_final(const float* __restrict__ ws, float* __restrict__ out) {
    __shared__ float ssum;
    int tid = threadIdx.x;
    if (tid < 64) {
        float v = (tid < 32) ? ws[OFF_SUMPART + tid * 32] : 0.f;
        v = wred_all(v);
        if (tid == 0) ssum = v;
    }
    __syncthreads();
    int g = blockIdx.x * 256 + tid;
    if (g >= VV + MOOV) return;
    float gp = ws[OFF_GENP];
    float pv = (g < VV) ? ws[OFF_LOGIT + g] / ssum : 0.f;
    float prob = gp * pv + ws[OFF_PCOPY + g];
    out[g] = logf(fmaxf(prob, 1e-10f));
}

extern "C" void kernel_launch(void* const* d_in, const int* in_sizes, int n_in,
                              void* d_out, int out_size, void* d_ws, size_t ws_size,
                              hipStream_t stream) {
    (void)in_sizes; (void)n_in; (void)out_size; (void)ws_size;
    const float* emb   = (const float*)d_in[0];
    const float* h0    = (const float*)d_in[1];
    const float* c0    = (const float*)d_in[2];
    const float* enc   = (const float*)d_in[3];
    const float* name  = (const float*)d_in[4];
    const float* type  = (const float*)d_in[5];
    const float* nameh = (const float*)d_in[6];
    const float* typeh = (const float*)d_in[7];
    const float* Wma   = (const float*)d_in[8];
    const float* bma   = (const float*)d_in[9];
    const float* Wmc   = (const float*)d_in[10];
    const float* bmc   = (const float*)d_in[11];
    const float* Wih   = (const float*)d_in[12];
    const float* Whh   = (const float*)d_in[13];
    const float* bih   = (const float*)d_in[14];
    const float* bhh   = (const float*)d_in[15];
    const float* Wcp   = (const float*)d_in[16];
    const float* bcp   = (const float*)d_in[17];
    const float* Wg    = (const float*)d_in[18];
    const float* bg    = (const float*)d_in[19];
    const float* Wout  = (const float*)d_in[20];
    const float* bout  = (const float*)d_in[21];
    const int*   tidx  = (const int*)d_in[22];
    float* out = (float*)d_out;
    float* ws  = (float*)d_ws;

    (void)hipMemsetAsync((char*)d_ws + OFF_CTR * sizeof(float), 0, sizeof(int), stream);

    k_init       <<<454,  256, 0, stream>>>(emb, Wma, bma, enc, name, Whh, bih, bhh, h0, ws);
    k_scores_ctx <<<160,  256, 0, stream>>>(enc, name, type, ws);
    k_x          <<<128,  256, 0, stream>>>(Wmc, bmc, ws);
    k_gates_lstm <<<64,   256, 0, stream>>>(Wih, c0, ws, out);
    k_big_all    <<<65 + NBIG + 8, 256, 0, stream>>>(Wout, bout, Wcp, bcp, nameh, typeh,
                                                     Wg, bg, type, tidx, ws);
    k_final      <<<197,  256, 0, stream>>>(ws, out);
}

// Round 13
// 72.951 us; speedup vs baseline: 7.6422x; 1.2478x over previous
//
#include <hip/hip_runtime.h>

#define VV   50257
#define EE   512
#define HH   1024
#define TT   512
#define SS   8
#define TSS  128
#define MOOV 20

// ws layout (floats)
#define OFF_Q      0        // 1024
#define OFF_COMB   1024     // 3584 : [emb(512) | acc_enc(1024) | acc_name(1024) | acc_type(1024)]
#define OFF_DENOM  4608     // 3 : unnormalized softmax denominators (enc, name, type)
#define OFF_SUMPART 4640    // 32 slots spaced 32 floats (128 B) for k_big partial sumexp
#define OFF_X      7168     // 512
#define OFF_H1     11776    // 1024
#define OFF_C1     12800    // 1024
#define OFF_GENP   13824    // 1
#define OFF_SIM    13832    // 8
#define OFF_QC     13840    // 1024
#define OFF_LOGIT  15888    // 50257 (stores exp(logit))
#define OFF_PCOPY  66148    // 50277 (scaled copy probs, zeroed each call)

#define NBIG 3142           // big blocks: 16 rows each (proven R5 shape)

__device__ __forceinline__ float dot4(float4 a, float4 b) {
    return a.x*b.x + a.y*b.y + a.z*b.z + a.w*b.w;
}
__device__ __forceinline__ float wred(float v) {
    #pragma unroll
    for (int o = 32; o; o >>= 1) v += __shfl_down(v, o, 64);
    return v;
}
__device__ __forceinline__ float wred_all(float v) {
    #pragma unroll
    for (int o = 32; o; o >>= 1) v += __shfl_xor(v, o, 64);
    return v;
}
__device__ __forceinline__ float wmax_all(float v) {
    #pragma unroll
    for (int o = 32; o; o >>= 1) v = fmaxf(v, __shfl_xor(v, o, 64));
    return v;
}

// R rows per wave, CH float4-chunks per lane per row; vector held in registers.
template<int R, int CH>
__device__ __forceinline__ void rowsN_dot(const float* __restrict__ W, int ld,
                                          int row0, int rowmax,
                                          const float4 vec[CH], int lane, float s[R]) {
    float4 w[R][CH];
    #pragma unroll
    for (int r = 0; r < R; ++r) {
        int row = row0 + r; if (row > rowmax) row = rowmax;
        const float4* Wr = (const float4*)(W + (size_t)row * ld);
        #pragma unroll
        for (int k = 0; k < CH; ++k) w[r][k] = Wr[lane + 64 * k];
    }
    #pragma unroll
    for (int r = 0; r < R; ++r) {
        float acc = 0.f;
        #pragma unroll
        for (int k = 0; k < CH; ++k) acc += dot4(w[r][k], vec[k]);
        s[r] = acc;
    }
}

// K1: zero scratch (comb acc, denoms, sumparts, pcopy), copy emb, q = W_ma_attn @ emb + b
__global__ void k_init_q(const float* __restrict__ emb, const float* __restrict__ W,
                         const float* __restrict__ bias, float* __restrict__ ws) {
    int tid = threadIdx.x, bid = blockIdx.x;
    int gid = bid * 256 + tid;
    if (gid < 3072) ws[OFF_COMB + 512 + gid] = 0.f;
    if (gid < 3)    ws[OFF_DENOM + gid] = 0.f;
    if (gid < 1024) ws[OFF_SUMPART + gid] = 0.f;
    if (gid < 512)  ws[OFF_COMB + gid] = emb[gid];
    if (gid < VV + MOOV) ws[OFF_PCOPY + gid] = 0.f;
    if (bid >= 64) return;
    int wave = tid >> 6, lane = tid & 63;
    const float4* e4 = (const float4*)emb;
    float4 ev[2] = { e4[lane], e4[lane + 64] };
    int row0 = (bid * 4 + wave) * 4;                   // < 1024
    float s[4];
    rowsN_dot<4, 2>(W, EE, row0, 1023, ev, lane, s);
    #pragma unroll
    for (int r = 0; r < 4; ++r) {
        float v = wred(s[r]);
        if (lane == 0) ws[OFF_Q + row0 + r] = v + bias[row0 + r];
    }
}

// K2: fused scores + unnormalized-softmax context accumulation (+ sim in block 160)
__global__ void k_scores_ctx(const float* __restrict__ enc, const float* __restrict__ name,
                             const float* __restrict__ type, float* __restrict__ ws) {
    int b = blockIdx.x, tid = threadIdx.x;
    int wave = tid >> 6, lane = tid & 63;
    if (b < 160) {
        const float* src; int seg, lb;
        if (b < 32)      { src = enc;  seg = 0; lb = b; }
        else if (b < 96) { src = name; seg = 1; lb = b - 32; }
        else             { src = type; seg = 2; lb = b - 96; }
        __shared__ float sc[16];
        const float4* q4 = (const float4*)(ws + OFF_Q);
        float4 qv[4] = { q4[lane], q4[lane + 64], q4[lane + 128], q4[lane + 192] };
        int r0 = lb * 16 + wave * 4;
        float s[4];
        rowsN_dot<4, 4>(src, HH, r0, 1 << 30, qv, lane, s);
        #pragma unroll
        for (int r = 0; r < 4; ++r) {
            float v = wred(s[r]);
            if (lane == 0) sc[wave * 4 + r] = __expf(v);
        }
        __syncthreads();
        float acc[4] = {0.f, 0.f, 0.f, 0.f};
        const float* base = src + (size_t)(lb * 16) * HH;
        #pragma unroll 4
        for (int r = 0; r < 16; ++r) {
            float er = sc[r];
            const float* row = base + (size_t)r * HH;
            #pragma unroll
            for (int c = 0; c < 4; ++c) acc[c] += er * row[tid + 256 * c];
        }
        float* dst = ws + OFF_COMB + 512 + seg * 1024;
        #pragma unroll
        for (int c = 0; c < 4; ++c) atomicAdd(&dst[tid + 256 * c], acc[c]);
        if (tid == 0) {
            float es = 0.f;
            for (int r = 0; r < 16; ++r) es += sc[r];
            atomicAdd(&ws[OFF_DENOM + seg], es);
        }
    } else {
        __shared__ float sd[8];
        const float4* el = (const float4*)(enc + (size_t)(TT - 1) * HH);
        for (int s8 = wave; s8 < 8; s8 += 4) {
            const float4* R = (const float4*)(name + ((size_t)s8 * TSS + (TSS - 1)) * HH);
            float s = 0.f;
            #pragma unroll
            for (int k = 0; k < 4; ++k) s += dot4(R[lane + 64 * k], el[lane + 64 * k]);
            s = wred(s);
            if (lane == 0) sd[s8] = s;
        }
        __syncthreads();
        if (tid == 0) {
            float m = -1e30f;
            for (int i = 0; i < 8; ++i) m = fmaxf(m, sd[i]);
            float e[8], su = 0.f;
            for (int i = 0; i < 8; ++i) { e[i] = __expf(sd[i] - m); su += e[i]; }
            for (int i = 0; i < 8; ++i) ws[OFF_SIM + i] = e[i] / su;
        }
    }
}

// K3: x = tanh(W_ma_comb @ (comb with per-segment 1/denom scaling) + b)
__global__ void k_x(const float* __restrict__ W, const float* __restrict__ bias,
                    float* __restrict__ ws) {
    int tid = threadIdx.x, wave = tid >> 6, lane = tid & 63;
    int row = blockIdx.x * 4 + wave;                   // < 512
    float inv1 = 1.f / ws[OFF_DENOM + 0];
    float inv2 = 1.f / ws[OFF_DENOM + 1];
    float inv3 = 1.f / ws[OFF_DENOM + 2];
    const float4* Wr = (const float4*)(W + (size_t)row * 3584);
    const float4* c4 = (const float4*)(ws + OFF_COMB);
    float s = 0.f;
    #pragma unroll
    for (int k = 0; k < 14; ++k) {
        int j = lane + 64 * k;
        float sc = (j < 128) ? 1.f : (j < 384) ? inv1 : (j < 640) ? inv2 : inv3;
        s += dot4(Wr[j], c4[j]) * sc;
    }
    s = wred(s);
    if (lane == 0) ws[OFF_X + row] = tanhf(s + bias[row]);
}

// K4: fused gates + LSTM cell — 256 blocks (full GPU), block b owns t in [b*4, b*4+4).
// Wave w computes gate w's 4 rows (one rowsN_dot pair; no grp loop).
__global__ void k_gates_lstm(const float* __restrict__ Wih, const float* __restrict__ Whh,
                             const float* __restrict__ bih, const float* __restrict__ bhh,
                             const float* __restrict__ h0, const float* __restrict__ c0,
                             float* __restrict__ ws, float* __restrict__ out) {
    __shared__ float g4[4][4];
    int tid = threadIdx.x, wave = tid >> 6, lane = tid & 63, b = blockIdx.x;
    const float4* x4 = (const float4*)(ws + OFF_X);
    float4 xv[2] = { x4[lane], x4[lane + 64] };
    const float4* h4 = (const float4*)h0;
    float4 hv[4] = { h4[lane], h4[lane + 64], h4[lane + 128], h4[lane + 192] };
    int row0 = wave * 1024 + b * 4;                    // gate `wave`, 4 rows
    float s1[4], s2[4];
    rowsN_dot<4, 2>(Wih, EE, row0, 4095, xv, lane, s1);
    rowsN_dot<4, 4>(Whh, HH, row0, 4095, hv, lane, s2);
    #pragma unroll
    for (int r = 0; r < 4; ++r) {
        float v = wred(s1[r] + s2[r]);
        int row = row0 + r;
        if (lane == 0) g4[wave][r] = v + bih[row] + bhh[row];
    }
    __syncthreads();
    if (tid < 4) {
        int t = b * 4 + tid;
        float ig = 1.f / (1.f + __expf(-g4[0][tid]));
        float fg = 1.f / (1.f + __expf(-g4[1][tid]));
        float gg = tanhf(g4[2][tid]);
        float og = 1.f / (1.f + __expf(-g4[3][tid]));
        float c1 = fg * c0[t] + ig * gg;
        float h1 = og * tanhf(c1);
        ws[OFF_H1 + t] = h1; ws[OFF_C1 + t] = c1;
        out[VV + MOOV + t] = h1;
        out[VV + MOOV + 1024 + t] = c1;
    }
}

// K5: fused [big matvec | qc | gen_p], all depend only on h1. (exact R5 shape)
__global__ void k_big_qc_genp(const float* __restrict__ W, const float* __restrict__ bias,
                              const float* __restrict__ Wcp, const float* __restrict__ bcp,
                              const float* __restrict__ nameh, const float* __restrict__ typeh,
                              const float* __restrict__ Wg, const float* __restrict__ bg,
                              float* __restrict__ ws) {
    int b = blockIdx.x, tid = threadIdx.x, wave = tid >> 6, lane = tid & 63;
    const float4* h4 = (const float4*)(ws + OFF_H1);
    if (b < NBIG) {
        float4 hv[4] = { h4[lane], h4[lane + 64], h4[lane + 128], h4[lane + 192] };
        int row0 = (b * 4 + wave) * 4;
        float s[4];
        rowsN_dot<4, 4>(W, HH, row0, VV - 1, hv, lane, s);
        float partial = 0.f;
        #pragma unroll
        for (int r = 0; r < 4; ++r) {
            float v = wred(s[r]);
            int row = row0 + r;
            if (lane == 0 && row < VV) {
                float e = __expf(v + bias[row]);
                ws[OFF_LOGIT + row] = e;
                partial += e;
            }
        }
        if (lane == 0) atomicAdd(&ws[OFF_SUMPART + (b & 31) * 32], partial);
    } else if (b < NBIG + 64) {
        int bb = b - NBIG;
        float4 hv[4] = { h4[lane], h4[lane + 64], h4[lane + 128], h4[lane + 192] };
        int row0 = (bb * 4 + wave) * 4;                 // < 1024
        float s[4];
        rowsN_dot<4, 4>(Wcp, HH, row0, 1023, hv, lane, s);
        #pragma unroll
        for (int r = 0; r < 4; ++r) {
            float v = wred(s[r]);
            if (lane == 0) ws[OFF_QC + row0 + r] = v + bcp[row0 + r];
        }
    } else {
        // gen_p = sigmoid(W_gen . [h1, name_h, type_h, x] + b_gen)
        float p = 0.f;
        #pragma unroll
        for (int j = 0; j < 14; ++j) {
            int k = tid + 256 * j;
            float cat = (k < 1024) ? ws[OFF_H1 + k]
                      : (k < 2048) ? nameh[k - 1024]
                      : (k < 3072) ? typeh[k - 2048]
                                   : ws[OFF_X + k - 3072];
            p += Wg[k] * cat;
        }
        __shared__ float red[4];
        float su = wred_all(p);
        if ((tid & 63) == 0) red[tid >> 6] = su;
        __syncthreads();
        if (tid == 0) {
            float ss = red[0] + red[1] + red[2] + red[3];
            ws[OFF_GENP] = 1.f / (1.f + __expf(-(ss + bg[0])));
        }
    }
}

// K6: per-s: scores = type_hiddens[s] @ qc, softmax, scale, scatter into pcopy
__global__ void k_attn_scatter(const float* __restrict__ type, const int* __restrict__ idx,
                               float* __restrict__ ws) {
    __shared__ float sc[TSS];
    __shared__ float sh_m, sh_s;
    int s = blockIdx.x, tid = threadIdx.x;
    int wave = tid >> 6, lane = tid & 63;
    const float4* q4 = (const float4*)(ws + OFF_QC);
    float4 qv[4] = { q4[lane], q4[lane + 64], q4[lane + 128], q4[lane + 192] };
    #pragma unroll
    for (int g = 0; g < 8; ++g) {
        int rloc = wave * 32 + g * 4;
        int r0 = s * TSS + rloc;
        float sv[4];
        rowsN_dot<4, 4>(type, HH, r0, 1 << 30, qv, lane, sv);
        #pragma unroll
        for (int r = 0; r < 4; ++r) {
            float v = wred(sv[r]);
            if (lane == 0) sc[rloc + r] = v;
        }
    }
    __syncthreads();
    if (wave == 0) {
        float v0 = sc[lane], v1 = sc[lane + 64];
        float m = wmax_all(fmaxf(v0, v1));
        float su = wred_all(__expf(v0 - m) + __expf(v1 - m));
        if (lane == 0) { sh_m = m; sh_s = su; }
    }
    __syncthreads();
    if (tid < TSS) {
        float scale = (1.f - ws[OFF_GENP]) * ws[OFF_SIM + s] / sh_s;
        float w = scale * __expf(sc[tid] - sh_m);
        atomicAdd(&ws[OFF_PCOPY + idx[s * TSS + tid]], w);
    }
}

// K7: out[v] = log(clip(gen_p * p_vocab[v] + p_copy[v]))
__global__ void k_final(const float* __restrict__ ws, float* __restrict__ out) {
    __shared__ float ssum;
    int tid = threadIdx.x;
    if (tid < 64) {
        float v = (tid < 32) ? ws[OFF_SUMPART + tid * 32] : 0.f;
        v = wred_all(v);
        if (tid == 0) ssum = v;
    }
    __syncthreads();
    int g = blockIdx.x * 256 + tid;
    if (g >= VV + MOOV) return;
    float gp = ws[OFF_GENP];
    float pv = (g < VV) ? ws[OFF_LOGIT + g] / ssum : 0.f;
    float prob = gp * pv + ws[OFF_PCOPY + g];
    out[g] = logf(fmaxf(prob, 1e-10f));
}

extern "C" void kernel_launch(void* const* d_in, const int* in_sizes, int n_in,
                              void* d_out, int out_size, void* d_ws, size_t ws_size,
                              hipStream_t stream) {
    (void)in_sizes; (void)n_in; (void)out_size; (void)ws_size;
    const float* emb   = (const float*)d_in[0];
    const float* h0    = (const float*)d_in[1];
    const float* c0    = (const float*)d_in[2];
    const float* enc   = (const float*)d_in[3];
    const float* name  = (const float*)d_in[4];
    const float* type  = (const float*)d_in[5];
    const float* nameh = (const float*)d_in[6];
    const float* typeh = (const float*)d_in[7];
    const float* Wma   = (const float*)d_in[8];
    const float* bma   = (const float*)d_in[9];
    const float* Wmc   = (const float*)d_in[10];
    const float* bmc   = (const float*)d_in[11];
    const float* Wih   = (const float*)d_in[12];
    const float* Whh   = (const float*)d_in[13];
    const float* bih   = (const float*)d_in[14];
    const float* bhh   = (const float*)d_in[15];
    const float* Wcp   = (const float*)d_in[16];
    const float* bcp   = (const float*)d_in[17];
    const float* Wg    = (const float*)d_in[18];
    const float* bg    = (const float*)d_in[19];
    const float* Wout  = (const float*)d_in[20];
    const float* bout  = (const float*)d_in[21];
    const int*   tidx  = (const int*)d_in[22];
    float* out = (float*)d_out;
    float* ws  = (float*)d_ws;

    k_init_q      <<<197,      256, 0, stream>>>(emb, Wma, bma, ws);
    k_scores_ctx  <<<161,      256, 0, stream>>>(enc, name, type, ws);
    k_x           <<<128,      256, 0, stream>>>(Wmc, bmc, ws);
    k_gates_lstm  <<<256,      256, 0, stream>>>(Wih, Whh, bih, bhh, h0, c0, ws, out);
    k_big_qc_genp <<<NBIG + 65, 256, 0, stream>>>(Wout, bout, Wcp, bcp, nameh, typeh, Wg, bg, ws);
    k_attn_scatter<<<8,        256, 0, stream>>>(type, tidx, ws);
    k_final       <<<197,      256, 0, stream>>>(ws, out);
}

// Round 14
// 72.601 us; speedup vs baseline: 7.6791x; 1.0048x over previous
//
#include <hip/hip_runtime.h>

#define VV   50257
#define EE   512
#define HH   1024
#define TT   512
#define SS   8
#define TSS  128
#define MOOV 20

// ws layout (floats)
#define OFF_Q      0        // 1024
#define OFF_COMB   1024     // 3584 : [emb(512) | acc_enc(1024) | acc_name(1024) | acc_type(1024)]
#define OFF_DENOM  4608     // 3 : unnormalized softmax denominators (enc, name, type)
#define OFF_SUMPART 4640    // 32 slots spaced 32 floats (128 B) for k_big partial sumexp
#define OFF_X      7168     // 512
#define OFF_H1     11776    // 1024
#define OFF_C1     12800    // 1024
#define OFF_GENP   13824    // 1
#define OFF_SIM    13832    // 8
#define OFF_QC     13840    // 1024
#define OFF_LOGIT  15888    // 50257 (stores exp(logit))
#define OFF_PCOPY  66148    // 50277 (scaled copy probs, zeroed each call)

#define NBIG 6283           // big blocks: 8 rows each (2 rows/wave — R-parameter test)

__device__ __forceinline__ float dot4(float4 a, float4 b) {
    return a.x*b.x + a.y*b.y + a.z*b.z + a.w*b.w;
}
__device__ __forceinline__ float wred(float v) {
    #pragma unroll
    for (int o = 32; o; o >>= 1) v += __shfl_down(v, o, 64);
    return v;
}
__device__ __forceinline__ float wred_all(float v) {
    #pragma unroll
    for (int o = 32; o; o >>= 1) v += __shfl_xor(v, o, 64);
    return v;
}
__device__ __forceinline__ float wmax_all(float v) {
    #pragma unroll
    for (int o = 32; o; o >>= 1) v = fmaxf(v, __shfl_xor(v, o, 64));
    return v;
}

// R rows per wave, CH float4-chunks per lane per row; vector held in registers.
template<int R, int CH>
__device__ __forceinline__ void rowsN_dot(const float* __restrict__ W, int ld,
                                          int row0, int rowmax,
                                          const float4 vec[CH], int lane, float s[R]) {
    float4 w[R][CH];
    #pragma unroll
    for (int r = 0; r < R; ++r) {
        int row = row0 + r; if (row > rowmax) row = rowmax;
        const float4* Wr = (const float4*)(W + (size_t)row * ld);
        #pragma unroll
        for (int k = 0; k < CH; ++k) w[r][k] = Wr[lane + 64 * k];
    }
    #pragma unroll
    for (int r = 0; r < R; ++r) {
        float acc = 0.f;
        #pragma unroll
        for (int k = 0; k < CH; ++k) acc += dot4(w[r][k], vec[k]);
        s[r] = acc;
    }
}

// K1: zero scratch (comb acc, denoms, sumparts, pcopy), copy emb, q = W_ma_attn @ emb + b
__global__ void k_init_q(const float* __restrict__ emb, const float* __restrict__ W,
                         const float* __restrict__ bias, float* __restrict__ ws) {
    int tid = threadIdx.x, bid = blockIdx.x;
    int gid = bid * 256 + tid;
    if (gid < 3072) ws[OFF_COMB + 512 + gid] = 0.f;
    if (gid < 3)    ws[OFF_DENOM + gid] = 0.f;
    if (gid < 1024) ws[OFF_SUMPART + gid] = 0.f;
    if (gid < 512)  ws[OFF_COMB + gid] = emb[gid];
    if (gid < VV + MOOV) ws[OFF_PCOPY + gid] = 0.f;
    if (bid >= 64) return;
    int wave = tid >> 6, lane = tid & 63;
    const float4* e4 = (const float4*)emb;
    float4 ev[2] = { e4[lane], e4[lane + 64] };
    int row0 = (bid * 4 + wave) * 4;                   // < 1024
    float s[4];
    rowsN_dot<4, 2>(W, EE, row0, 1023, ev, lane, s);
    #pragma unroll
    for (int r = 0; r < 4; ++r) {
        float v = wred(s[r]);
        if (lane == 0) ws[OFF_Q + row0 + r] = v + bias[row0 + r];
    }
}

// K2: fused scores + unnormalized-softmax context accumulation (+ sim in block 160)
__global__ void k_scores_ctx(const float* __restrict__ enc, const float* __restrict__ name,
                             const float* __restrict__ type, float* __restrict__ ws) {
    int b = blockIdx.x, tid = threadIdx.x;
    int wave = tid >> 6, lane = tid & 63;
    if (b < 160) {
        const float* src; int seg, lb;
        if (b < 32)      { src = enc;  seg = 0; lb = b; }
        else if (b < 96) { src = name; seg = 1; lb = b - 32; }
        else             { src = type; seg = 2; lb = b - 96; }
        __shared__ float sc[16];
        const float4* q4 = (const float4*)(ws + OFF_Q);
        float4 qv[4] = { q4[lane], q4[lane + 64], q4[lane + 128], q4[lane + 192] };
        int r0 = lb * 16 + wave * 4;
        float s[4];
        rowsN_dot<4, 4>(src, HH, r0, 1 << 30, qv, lane, s);
        #pragma unroll
        for (int r = 0; r < 4; ++r) {
            float v = wred(s[r]);
            if (lane == 0) sc[wave * 4 + r] = __expf(v);
        }
        __syncthreads();
        float acc[4] = {0.f, 0.f, 0.f, 0.f};
        const float* base = src + (size_t)(lb * 16) * HH;
        #pragma unroll 4
        for (int r = 0; r < 16; ++r) {
            float er = sc[r];
            const float* row = base + (size_t)r * HH;
            #pragma unroll
            for (int c = 0; c < 4; ++c) acc[c] += er * row[tid + 256 * c];
        }
        float* dst = ws + OFF_COMB + 512 + seg * 1024;
        #pragma unroll
        for (int c = 0; c < 4; ++c) atomicAdd(&dst[tid + 256 * c], acc[c]);
        if (tid == 0) {
            float es = 0.f;
            for (int r = 0; r < 16; ++r) es += sc[r];
            atomicAdd(&ws[OFF_DENOM + seg], es);
        }
    } else {
        __shared__ float sd[8];
        const float4* el = (const float4*)(enc + (size_t)(TT - 1) * HH);
        for (int s8 = wave; s8 < 8; s8 += 4) {
            const float4* R = (const float4*)(name + ((size_t)s8 * TSS + (TSS - 1)) * HH);
            float s = 0.f;
            #pragma unroll
            for (int k = 0; k < 4; ++k) s += dot4(R[lane + 64 * k], el[lane + 64 * k]);
            s = wred(s);
            if (lane == 0) sd[s8] = s;
        }
        __syncthreads();
        if (tid == 0) {
            float m = -1e30f;
            for (int i = 0; i < 8; ++i) m = fmaxf(m, sd[i]);
            float e[8], su = 0.f;
            for (int i = 0; i < 8; ++i) { e[i] = __expf(sd[i] - m); su += e[i]; }
            for (int i = 0; i < 8; ++i) ws[OFF_SIM + i] = e[i] / su;
        }
    }
}

// K3: x = tanh(W_ma_comb @ (comb with per-segment 1/denom scaling) + b)
__global__ void k_x(const float* __restrict__ W, const float* __restrict__ bias,
                    float* __restrict__ ws) {
    int tid = threadIdx.x, wave = tid >> 6, lane = tid & 63;
    int row = blockIdx.x * 4 + wave;                   // < 512
    float inv1 = 1.f / ws[OFF_DENOM + 0];
    float inv2 = 1.f / ws[OFF_DENOM + 1];
    float inv3 = 1.f / ws[OFF_DENOM + 2];
    const float4* Wr = (const float4*)(W + (size_t)row * 3584);
    const float4* c4 = (const float4*)(ws + OFF_COMB);
    float s = 0.f;
    #pragma unroll
    for (int k = 0; k < 14; ++k) {
        int j = lane + 64 * k;
        float sc = (j < 128) ? 1.f : (j < 384) ? inv1 : (j < 640) ? inv2 : inv3;
        s += dot4(Wr[j], c4[j]) * sc;
    }
    s = wred(s);
    if (lane == 0) ws[OFF_X + row] = tanhf(s + bias[row]);
}

// K4: fused gates + LSTM cell — 256 blocks (full GPU), block b owns t in [b*4, b*4+4).
__global__ void k_gates_lstm(const float* __restrict__ Wih, const float* __restrict__ Whh,
                             const float* __restrict__ bih, const float* __restrict__ bhh,
                             const float* __restrict__ h0, const float* __restrict__ c0,
                             float* __restrict__ ws, float* __restrict__ out) {
    __shared__ float g4[4][4];
    int tid = threadIdx.x, wave = tid >> 6, lane = tid & 63, b = blockIdx.x;
    const float4* x4 = (const float4*)(ws + OFF_X);
    float4 xv[2] = { x4[lane], x4[lane + 64] };
    const float4* h4 = (const float4*)h0;
    float4 hv[4] = { h4[lane], h4[lane + 64], h4[lane + 128], h4[lane + 192] };
    int row0 = wave * 1024 + b * 4;                    // gate `wave`, 4 rows
    float s1[4], s2[4];
    rowsN_dot<4, 2>(Wih, EE, row0, 4095, xv, lane, s1);
    rowsN_dot<4, 4>(Whh, HH, row0, 4095, hv, lane, s2);
    #pragma unroll
    for (int r = 0; r < 4; ++r) {
        float v = wred(s1[r] + s2[r]);
        int row = row0 + r;
        if (lane == 0) g4[wave][r] = v + bih[row] + bhh[row];
    }
    __syncthreads();
    if (tid < 4) {
        int t = b * 4 + tid;
        float ig = 1.f / (1.f + __expf(-g4[0][tid]));
        float fg = 1.f / (1.f + __expf(-g4[1][tid]));
        float gg = tanhf(g4[2][tid]);
        float og = 1.f / (1.f + __expf(-g4[3][tid]));
        float c1 = fg * c0[t] + ig * gg;
        float h1 = og * tanhf(c1);
        ws[OFF_H1 + t] = h1; ws[OFF_C1 + t] = c1;
        out[VV + MOOV + t] = h1;
        out[VV + MOOV + 1024 + t] = c1;
    }
}

// K5: fused [big matvec | qc | gen_p]. Big part: 2 rows/wave, 8 rows/block (R-test).
__global__ void k_big_qc_genp(const float* __restrict__ W, const float* __restrict__ bias,
                              const float* __restrict__ Wcp, const float* __restrict__ bcp,
                              const float* __restrict__ nameh, const float* __restrict__ typeh,
                              const float* __restrict__ Wg, const float* __restrict__ bg,
                              float* __restrict__ ws) {
    int b = blockIdx.x, tid = threadIdx.x, wave = tid >> 6, lane = tid & 63;
    const float4* h4 = (const float4*)(ws + OFF_H1);
    if (b < NBIG) {
        float4 hv[4] = { h4[lane], h4[lane + 64], h4[lane + 128], h4[lane + 192] };
        int row0 = (b * 4 + wave) * 2;
        float s[2];
        rowsN_dot<2, 4>(W, HH, row0, VV - 1, hv, lane, s);
        float partial = 0.f;
        #pragma unroll
        for (int r = 0; r < 2; ++r) {
            float v = wred(s[r]);
            int row = row0 + r;
            if (lane == 0 && row < VV) {
                float e = __expf(v + bias[row]);
                ws[OFF_LOGIT + row] = e;
                partial += e;
            }
        }
        if (lane == 0) atomicAdd(&ws[OFF_SUMPART + (b & 31) * 32], partial);
    } else if (b < NBIG + 64) {
        int bb = b - NBIG;
        float4 hv[4] = { h4[lane], h4[lane + 64], h4[lane + 128], h4[lane + 192] };
        int row0 = (bb * 4 + wave) * 4;                 // < 1024
        float s[4];
        rowsN_dot<4, 4>(Wcp, HH, row0, 1023, hv, lane, s);
        #pragma unroll
        for (int r = 0; r < 4; ++r) {
            float v = wred(s[r]);
            if (lane == 0) ws[OFF_QC + row0 + r] = v + bcp[row0 + r];
        }
    } else {
        // gen_p = sigmoid(W_gen . [h1, name_h, type_h, x] + b_gen)
        float p = 0.f;
        #pragma unroll
        for (int j = 0; j < 14; ++j) {
            int k = tid + 256 * j;
            float cat = (k < 1024) ? ws[OFF_H1 + k]
                      : (k < 2048) ? nameh[k - 1024]
                      : (k < 3072) ? typeh[k - 2048]
                                   : ws[OFF_X + k - 3072];
            p += Wg[k] * cat;
        }
        __shared__ float red[4];
        float su = wred_all(p);
        if ((tid & 63) == 0) red[tid >> 6] = su;
        __syncthreads();
        if (tid == 0) {
            float ss = red[0] + red[1] + red[2] + red[3];
            ws[OFF_GENP] = 1.f / (1.f + __expf(-(ss + bg[0])));
        }
    }
}

// K6: per-s: scores = type_hiddens[s] @ qc, softmax, scale, scatter into pcopy
__global__ void k_attn_scatter(const float* __restrict__ type, const int* __restrict__ idx,
                               float* __restrict__ ws) {
    __shared__ float sc[TSS];
    __shared__ float sh_m, sh_s;
    int s = blockIdx.x, tid = threadIdx.x;
    int wave = tid >> 6, lane = tid & 63;
    const float4* q4 = (const float4*)(ws + OFF_QC);
    float4 qv[4] = { q4[lane], q4[lane + 64], q4[lane + 128], q4[lane + 192] };
    #pragma unroll
    for (int g = 0; g < 8; ++g) {
        int rloc = wave * 32 + g * 4;
        int r0 = s * TSS + rloc;
        float sv[4];
        rowsN_dot<4, 4>(type, HH, r0, 1 << 30, qv, lane, sv);
        #pragma unroll
        for (int r = 0; r < 4; ++r) {
            float v = wred(sv[r]);
            if (lane == 0) sc[rloc + r] = v;
        }
    }
    __syncthreads();
    if (wave == 0) {
        float v0 = sc[lane], v1 = sc[lane + 64];
        float m = wmax_all(fmaxf(v0, v1));
        float su = wred_all(__expf(v0 - m) + __expf(v1 - m));
        if (lane == 0) { sh_m = m; sh_s = su; }
    }
    __syncthreads();
    if (tid < TSS) {
        float scale = (1.f - ws[OFF_GENP]) * ws[OFF_SIM + s] / sh_s;
        float w = scale * __expf(sc[tid] - sh_m);
        atomicAdd(&ws[OFF_PCOPY + idx[s * TSS + tid]], w);
    }
}

// K7: out[v] = log(clip(gen_p * p_vocab[v] + p_copy[v]))
__global__ void k_final(const float* __restrict__ ws, float* __restrict__ out) {
    __shared__ float ssum;
    int tid = threadIdx.x;
    if (tid < 64) {
        float v = (tid < 32) ? ws[OFF_SUMPART + tid * 32] : 0.f;
        v = wred_all(v);
        if (tid == 0) ssum = v;
    }
    __syncthreads();
    int g = blockIdx.x * 256 + tid;
    if (g >= VV + MOOV) return;
    float gp = ws[OFF_GENP];
    float pv = (g < VV) ? ws[OFF_LOGIT + g] / ssum : 0.f;
    float prob = gp * pv + ws[OFF_PCOPY + g];
    out[g] = logf(fmaxf(prob, 1e-10f));
}

extern "C" void kernel_launch(void* const* d_in, const int* in_sizes, int n_in,
                              void* d_out, int out_size, void* d_ws, size_t ws_size,
                              hipStream_t stream) {
    (void)in_sizes; (void)n_in; (void)out_size; (void)ws_size;
    const float* emb   = (const float*)d_in[0];
    const float* h0    = (const float*)d_in[1];
    const float* c0    = (const float*)d_in[2];
    const float* enc   = (const float*)d_in[3];
    const float* name  = (const float*)d_in[4];
    const float* type  = (const float*)d_in[5];
    const float* nameh = (const float*)d_in[6];
    const float* typeh = (const float*)d_in[7];
    const float* Wma   = (const float*)d_in[8];
    const float* bma   = (const float*)d_in[9];
    const float* Wmc   = (const float*)d_in[10];
    const float* bmc   = (const float*)d_in[11];
    const float* Wih   = (const float*)d_in[12];
    const float* Whh   = (const float*)d_in[13];
    const float* bih   = (const float*)d_in[14];
    const float* bhh   = (const float*)d_in[15];
    const float* Wcp   = (const float*)d_in[16];
    const float* bcp   = (const float*)d_in[17];
    const float* Wg    = (const float*)d_in[18];
    const float* bg    = (const float*)d_in[19];
    const float* Wout  = (const float*)d_in[20];
    const float* bout  = (const float*)d_in[21];
    const int*   tidx  = (const int*)d_in[22];
    float* out = (float*)d_out;
    float* ws  = (float*)d_ws;

    k_init_q      <<<197,      256, 0, stream>>>(emb, Wma, bma, ws);
    k_scores_ctx  <<<161,      256, 0, stream>>>(enc, name, type, ws);
    k_x           <<<128,      256, 0, stream>>>(Wmc, bmc, ws);
    k_gates_lstm  <<<256,      256, 0, stream>>>(Wih, Whh, bih, bhh, h0, c0, ws, out);
    k_big_qc_genp <<<NBIG + 65, 256, 0, stream>>>(Wout, bout, Wcp, bcp, nameh, typeh, Wg, bg, ws);
    k_attn_scatter<<<8,        256, 0, stream>>>(type, tidx, ws);
    k_final       <<<197,      256, 0, stream>>>(ws, out);
}